// Round 10
// baseline (145.696 us; speedup 1.0000x reference)
//
#include <hip/hip_runtime.h>
#include <stdint.h>

#define BATCH 8
#define HIN   28
#define CH    32
#define HO    14
#define NIN   784                 // 28*28
#define NOUT  196                 // 14*14
#define ROW_W (NIN * CH)          // 25088 floats per Sigma spatial row
#define JH    392                 // j-positions per block (j-half)
#define JS    196                 // j-positions per stage
#define STG_W (JS * CH)           // 6272 floats = 25088 B per stage
#define TILE_W (NOUT * CH)        // 6272 output words per (b,p)

typedef float f32x4 __attribute__((ext_vector_type(4)));

// Block = (b, p, jhalf), 1024 threads, LDS = 2x25KB stage dbuf + colsel
// (62.7KB -> 2 blocks/CU). Counted-vmcnt pipeline (T3/T4): DMA stage s+1 is
// issued BEFORE consuming stage s; the wait is a counted s_waitcnt vmcnt(n)
// (n = this wave's own in-flight chunks for s+1) + raw s_barrier, so 25KB of
// DMA stays in flight across every barrier; no full vmcnt(0) drain in the
// main loop. Stage s covers Sigma[i_{s>>1}, jh*392+(s&1)*196 .. +196, :].
// Prologue DMA for stage 0 issues before phase 0 (argmax) and is drained by
// phase 0's __syncthreads.
// Gather: thread owns (q = tid>>5 + 32k, c = tid&31); 7 conflict-free
// ds_read_b32 + cndmask into register acc per stage. Store: predicated
// coalesced NT stores; each global word written by exactly one (stage,jhalf)
// -> no init, no atomics, deterministic.
__global__ __launch_bounds__(1024, 2) void vdp_pool_pipe_kernel(
        const float* __restrict__ mu_in,
        const float* __restrict__ sigma_in,
        float* __restrict__ mu_out,
        float* __restrict__ sigma_out)
{
    __shared__ __align__(16) float buf[2][STG_W];    // 50176 B
    __shared__ uint16_t colsel[TILE_W];              // 12544 B

    const int bid = blockIdx.x;
    const int jh  = bid & 1;                 // j-half
    const int bp  = bid >> 1;                // b*NOUT + p
    const int b   = bp / NOUT;
    const int p   = bp - b * NOUT;
    const int tid = threadIdx.x;
    const int w   = tid >> 6;                // wave 0..15
    const int l   = tid & 63;                // lane
    const int py  = p / HO, px = p - py * HO;

    // -------- DMA issue for stage s (wave-uniform LDS base + lane*size) ----
    auto issue = [&](int s) {
        const int rr  = s >> 1;              // candidate row r
        const int i_r = (2 * py + (rr >> 1)) * HIN + 2 * px + (rr & 1);
        const float* src = sigma_in + ((size_t)b * NIN + i_r) * ROW_W
                         + (size_t)(jh * JH + (s & 1) * JS) * CH;
        float* dst = buf[s & 1];
        if (w < 10) {                        // 2 x 1KB chunks
            __builtin_amdgcn_global_load_lds(
                (const __attribute__((address_space(1))) void*)(src + w * 512 + l * 4),
                (__attribute__((address_space(3))) void*)(dst + w * 512 + l * 4),
                16, 0, 0);
            __builtin_amdgcn_global_load_lds(
                (const __attribute__((address_space(1))) void*)(src + w * 512 + 256 + l * 4),
                (__attribute__((address_space(3))) void*)(dst + w * 512 + 256 + l * 4),
                16, 0, 0);
        } else if (w < 14) {                 // 1 x 1KB chunk
            const int off = 5120 + (w - 10) * 256;
            __builtin_amdgcn_global_load_lds(
                (const __attribute__((address_space(1))) void*)(src + off + l * 4),
                (__attribute__((address_space(3))) void*)(dst + off + l * 4),
                16, 0, 0);
        } else {                             // 1 x 256B chunk
            const int off = 6144 + (w - 14) * 64;
            __builtin_amdgcn_global_load_lds(
                (const __attribute__((address_space(1))) void*)(src + off + l),
                (__attribute__((address_space(3))) void*)(dst + off + l),
                4, 0, 0);
        }
    };

    // -------- prologue: stage-0 DMA in flight under phase 0 ----------------
    issue(0);

    // -------- Phase 0: window argmax codes -> colsel (+ mu_out) ------------
    if (tid < NOUT * 2) {
        const int q2 = tid >> 1, hf = tid & 1;
        const int qy = q2 / HO, qx = q2 - qy * HO;
        const float* base =
            mu_in + (((size_t)b * HIN + 2 * qy) * HIN + 2 * qx) * CH + hf * 16;
        const int jb = (2 * qy) * HIN + 2 * qx;

        #pragma unroll
        for (int g = 0; g < 4; ++g) {
            const float4 v0 = *(const float4*)(base + g * 4);
            const float4 v1 = *(const float4*)(base + CH + g * 4);
            const float4 v2 = *(const float4*)(base + HIN * CH + g * 4);
            const float4 v3 = *(const float4*)(base + HIN * CH + CH + g * 4);
            float m0, m1, m2, m3;
            uint32_t k0, k1, k2, k3;
            { float best = v0.x; uint32_t k = 0;
              if (v1.x > best) { best = v1.x; k = 1; }      // strict > : TF ties
              if (v2.x > best) { best = v2.x; k = 2; }
              if (v3.x > best) { best = v3.x; k = 3; }
              m0 = best; k0 = k; }
            { float best = v0.y; uint32_t k = 0;
              if (v1.y > best) { best = v1.y; k = 1; }
              if (v2.y > best) { best = v2.y; k = 2; }
              if (v3.y > best) { best = v3.y; k = 3; }
              m1 = best; k1 = k; }
            { float best = v0.z; uint32_t k = 0;
              if (v1.z > best) { best = v1.z; k = 1; }
              if (v2.z > best) { best = v2.z; k = 2; }
              if (v3.z > best) { best = v3.z; k = 3; }
              m2 = best; k2 = k; }
            { float best = v0.w; uint32_t k = 0;
              if (v1.w > best) { best = v1.w; k = 1; }
              if (v2.w > best) { best = v2.w; k = 2; }
              if (v3.w > best) { best = v3.w; k = 3; }
              m3 = best; k3 = k; }
            const int cb = q2 * CH + hf * 16 + g * 4;
            colsel[cb + 0] = (uint16_t)(jb + (int)(k0 >> 1) * HIN + (int)(k0 & 1));
            colsel[cb + 1] = (uint16_t)(jb + (int)(k1 >> 1) * HIN + (int)(k1 & 1));
            colsel[cb + 2] = (uint16_t)(jb + (int)(k2 >> 1) * HIN + (int)(k2 & 1));
            colsel[cb + 3] = (uint16_t)(jb + (int)(k3 >> 1) * HIN + (int)(k3 & 1));
            if (q2 == p) {
                *(float4*)(mu_out + (size_t)bp * CH + hf * 16 + g * 4) =
                    make_float4(m0, m1, m2, m3);
            }
        }
    }
    __syncthreads();     // drains stage-0 DMA (vmcnt 0) + publishes colsel

    // -------- per-thread constants -----------------------------------------
    const int c   = tid & 31;                // channel
    const int qb0 = tid >> 5;                // 0..31

    uint16_t jcol[7];
    #pragma unroll
    for (int k = 0; k < 7; ++k) {
        const int q = qb0 + 32 * k;
        jcol[k] = (q < NOUT) ? colsel[q * CH + c] : (uint16_t)0;
    }
    const int jrow = (int)colsel[p * CH + c];   // selected input row for (p,c)

    float acc[7] = {0, 0, 0, 0, 0, 0, 0};

    // -------- main pipeline: 8 stages, counted-vmcnt, no full drains -------
    #pragma unroll
    for (int s = 0; s < 8; ++s) {
        if (s < 7) issue(s + 1);
        // wait only for THIS wave's stage-s chunks (s+1's stay in flight)
        if (s == 7) {
            asm volatile("s_waitcnt vmcnt(0)" ::: "memory");
        } else if (w < 10) {
            asm volatile("s_waitcnt vmcnt(2)" ::: "memory");
        } else {
            asm volatile("s_waitcnt vmcnt(1)" ::: "memory");
        }
        __builtin_amdgcn_sched_barrier(0);
        asm volatile("s_barrier" ::: "memory");   // stage s fully in LDS
        __builtin_amdgcn_sched_barrier(0);

        const int rr  = s >> 1;
        const int i_r = (2 * py + (rr >> 1)) * HIN + 2 * px + (rr & 1);
        const int jsl = jh * JH + (s & 1) * JS;
        const float* bpB = buf[s & 1];
        const bool rhit = (jrow == i_r);
        #pragma unroll
        for (int k = 0; k < 7; ++k) {
            const int  jl   = (int)jcol[k] - jsl;
            const bool mine = (unsigned)jl < (unsigned)JS;
            const float v   = bpB[(mine ? jl : 0) * CH + c]; // bank=c, free
            acc[k] = (rhit && mine) ? v : acc[k];
        }
        // own ds_reads must land before anyone overwrites this buffer
        asm volatile("s_waitcnt lgkmcnt(0)" ::: "memory");
        __builtin_amdgcn_sched_barrier(0);
        asm volatile("s_barrier" ::: "memory");
        __builtin_amdgcn_sched_barrier(0);
    }

    // -------- store: one owner per word, coalesced NT ----------------------
    float* ob = sigma_out + (size_t)bp * TILE_W;
    #pragma unroll
    for (int k = 0; k < 7; ++k) {
        const int q  = qb0 + 32 * k;
        const int jl = (int)jcol[k] - jh * JH;
        if (q < NOUT && (unsigned)jl < (unsigned)JH)
            __builtin_nontemporal_store(acc[k], ob + q * CH + c);
    }
}

extern "C" void kernel_launch(void* const* d_in, const int* in_sizes, int n_in,
                              void* d_out, int out_size, void* d_ws, size_t ws_size,
                              hipStream_t stream) {
    const float* mu_in    = (const float*)d_in[0];
    const float* sigma_in = (const float*)d_in[1];

    float* mu_out    = (float*)d_out;                      // 8*14*14*32 floats
    float* sigma_out = (float*)d_out + BATCH * NOUT * CH;  // 8*196*196*32 floats

    vdp_pool_pipe_kernel<<<BATCH * NOUT * 2, 1024, 0, stream>>>(
        mu_in, sigma_in, mu_out, sigma_out);
}

// Round 11
// 124.488 us; speedup vs baseline: 1.1704x; 1.1704x over previous
//
#include <hip/hip_runtime.h>
#include <stdint.h>

#define BATCH 8
#define HIN   28
#define CH    32
#define HO    14
#define NIN   784                 // 28*28
#define NOUT  196                 // 14*14
#define JHALF 392                 // contiguous j-columns per q-half
#define HTILE (98 * CH)           // 3136 words = 12.5KB output half-tile
#define NITEM (4 * JHALF * 8)     // 12544 16B-items per block
#define UNROLL 7
#define OUTER  (NITEM / 256 / UNROLL)  // 7

typedef float f32x4 __attribute__((ext_vector_type(4)));

// Block = (b, p, qh) where qh = output-row half (qy<7 / qy>=7).
// Key geometry: window q needs input cols j with pool(j)=q, and qy<7 <->
// jy<14 <-> j<392: both the input columns (4 rows x 50KB contiguous) and the
// output words (contiguous 12.5KB half-tile, single owner -> full-line NT
// writes) split cleanly. Half-blocks are small (16KB LDS, 4 waves) -> 6
// blocks/CU, 24 waves/CU with NO cross-wave barriers during the stream:
// demand gaps decorrelate across blocks (R9's 2-block/CU barrier-synced
// drains were the suspected residual).
// Phase 0: argmax codes for our 98 windows (+ window p) only.
// Phase 1: dense NT register stream, 7 loads in flight, branchless
//          trash-slot LDS scatter (e=tid&7 is thread-constant).
// Phase 2: half-tile -> global, contiguous, NT.
__global__ __launch_bounds__(256, 6) void vdp_pool_half_kernel(
        const float* __restrict__ mu_in,
        const float* __restrict__ sigma_in,
        float* __restrict__ mu_out,
        float* __restrict__ sigma_out)
{
    __shared__ __align__(16) float out_tile[HTILE + 64];   // +64 trash words
    __shared__ uint32_t cmq[JHALF * 2];                    // [jl][half16]
    __shared__ uint32_t pmask[2];                          // window-p codes

    const int bid = blockIdx.x;
    const int qh  = bid & 1;                 // output-row half
    const int bp  = bid >> 1;                // b*NOUT + p
    const int b   = bp / NOUT;
    const int p   = bp - b * NOUT;
    const int tid = threadIdx.x;
    const int py  = p / HO, px = p - py * HO;

    // ---------------- Phase 0: codes for our 98 windows + window p ----------
    if (tid < 198) {
        const int isP = (tid >= 196);
        int qy, qx, hf, ql;
        if (isP) { hf = tid - 196; qy = py; qx = px; ql = 0; }
        else     { ql = tid >> 1; hf = tid & 1;
                   const int qyl = ql / HO; qx = ql - qyl * HO; qy = qh * 7 + qyl; }

        const float* base =
            mu_in + (((size_t)b * HIN + 2 * qy) * HIN + 2 * qx) * CH + hf * 16;

        uint32_t kqh = 0;
        float mu4[4][4];
        #pragma unroll
        for (int g = 0; g < 4; ++g) {
            const float4 v0 = *(const float4*)(base + g * 4);
            const float4 v1 = *(const float4*)(base + CH + g * 4);
            const float4 v2 = *(const float4*)(base + HIN * CH + g * 4);
            const float4 v3 = *(const float4*)(base + HIN * CH + CH + g * 4);
            #pragma unroll
            for (int m = 0; m < 4; ++m) {
                const float e0 = (&v0.x)[m], e1 = (&v1.x)[m],
                            e2 = (&v2.x)[m], e3 = (&v3.x)[m];
                float best = e0; uint32_t k = 0;
                if (e1 > best) { best = e1; k = 1; }   // strict >: TF tie rule
                if (e2 > best) { best = e2; k = 2; }
                if (e3 > best) { best = e3; k = 3; }
                mu4[g][m] = best;
                kqh |= k << (2 * (g * 4 + m));
            }
        }
        if (isP) {
            pmask[hf] = kqh;
            if (((py < 7) ? 0 : 1) == qh) {            // unique mu_out owner
                #pragma unroll
                for (int g = 0; g < 4; ++g)
                    *(float4*)(mu_out + (size_t)bp * CH + hf * 16 + g * 4) =
                        make_float4(mu4[g][0], mu4[g][1], mu4[g][2], mu4[g][3]);
            }
        } else {
            const int jbl = (2 * qy) * HIN + 2 * qx - qh * JHALF;  // local j
            const uint32_t qb = (uint32_t)(ql * CH) << 16;
            #pragma unroll
            for (int dj = 0; dj < 4; ++dj) {
                uint32_t mm = 0;
                #pragma unroll
                for (int cl = 0; cl < 16; ++cl)
                    mm |= (((kqh >> (2 * cl)) & 3u) == (uint32_t)dj)
                          ? (1u << cl) : 0u;
                const int jl = jbl + (dj >> 1) * HIN + (dj & 1);
                cmq[jl * 2 + hf] = qb | mm;
            }
        }
    }
    __syncthreads();

    // ---------------- per-thread constants ----------------------------------
    const uint32_t e      = (uint32_t)tid & 7u;        // 16B chunk in 128B row
    const uint32_t half16 = e >> 2;                    // channel half
    const uint32_t shs    = (e & 3u) * 4u;             // nibble shift
    const uint32_t hw     = e * 4u;                    // word offset in row
    const uint32_t posb   = (uint32_t)tid >> 3;        // 0..31
    const uint32_t ibase  = (uint32_t)(2 * py) * HIN + 2u * px;
    const uint32_t trash  = HTILE + ((uint32_t)tid & 63u);

    // 4 x 16-bit row masks for this thread's channel half, from window p code
    const uint32_t pm = pmask[half16];
    unsigned long long rmpack = 0ull;
    #pragma unroll
    for (int r = 0; r < 4; ++r) {
        uint32_t mm = 0;
        #pragma unroll
        for (int cl = 0; cl < 16; ++cl)
            mm |= (((pm >> (2 * cl)) & 3u) == (uint32_t)r) ? (1u << cl) : 0u;
        rmpack |= (unsigned long long)mm << (16 * r);
    }

    // ---------------- Phase 1: dense NT stream + branchless LDS scatter -----
    const float* sb = sigma_in + (size_t)b * NIN * NIN * CH
                    + (size_t)qh * JHALF * CH;         // col-half base
    for (int o = 0; o < OUTER; ++o) {
        f32x4    val[UNROLL];
        uint32_t tab[UNROLL];
        uint32_t rmv[UNROLL];
        #pragma unroll
        for (int u = 0; u < UNROLL; ++u) {
            const uint32_t pos = (uint32_t)(o * UNROLL + u) * 32u + posb;
            const uint32_t r   = pos / JHALF;          // magic-mul
            const uint32_t jl  = pos - r * JHALF;
            const uint32_t i   = ibase + (r >> 1) * HIN + (r & 1u);
            val[u] = __builtin_nontemporal_load(
                (const f32x4*)(sb + ((size_t)i * NIN + jl) * CH + hw));
            tab[u] = cmq[jl * 2 + half16];
            rmv[u] = (uint32_t)(rmpack >> (r * 16u)) & 0xFFFFu;
        }
        #pragma unroll
        for (int u = 0; u < UNROLL; ++u) {
            const uint32_t sel16 = rmv[u] & (tab[u] & 0xFFFFu);
            const uint32_t s4    = (sel16 >> shs) & 0xFu;
            const uint32_t bs    = (tab[u] >> 16) + hw;
            out_tile[(s4 & 1u) ? bs + 0u : trash] = val[u][0];
            out_tile[(s4 & 2u) ? bs + 1u : trash] = val[u][1];
            out_tile[(s4 & 4u) ? bs + 2u : trash] = val[u][2];
            out_tile[(s4 & 8u) ? bs + 3u : trash] = val[u][3];
        }
    }
    __syncthreads();

    // ---------------- Phase 2: contiguous NT half-tile write-out ------------
    {
        const f32x4* srcT = (const f32x4*)out_tile;
        f32x4* dstT = (f32x4*)(sigma_out + (size_t)bp * (NOUT * CH)
                               + (size_t)qh * HTILE);
        for (int w = tid; w < HTILE / 4; w += 256)     // 784 f32x4
            __builtin_nontemporal_store(srcT[w], &dstT[w]);
    }
}

extern "C" void kernel_launch(void* const* d_in, const int* in_sizes, int n_in,
                              void* d_out, int out_size, void* d_ws, size_t ws_size,
                              hipStream_t stream) {
    const float* mu_in    = (const float*)d_in[0];
    const float* sigma_in = (const float*)d_in[1];

    float* mu_out    = (float*)d_out;                      // 8*14*14*32 floats
    float* sigma_out = (float*)d_out + BATCH * NOUT * CH;  // 8*196*196*32 floats

    vdp_pool_half_kernel<<<BATCH * NOUT * 2, 256, 0, stream>>>(
        mu_in, sigma_in, mu_out, sigma_out);
}

// Round 13
// 117.370 us; speedup vs baseline: 1.2413x; 1.0606x over previous
//
#include <hip/hip_runtime.h>
#include <stdint.h>

#define BATCH 8
#define HIN   28
#define CH    32
#define HO    14
#define NIN   784                 // 28*28
#define NOUT  196                 // 14*14
#define JHALF 392                 // contiguous j-columns per q-half
#define HTILE (98 * CH)           // 3136 words = 12.5KB output half-tile
#define UNROLL 7
#define OUTER  7                  // 49 items/thread x 256 thr = 12544 items

typedef float f32x4 __attribute__((ext_vector_type(4)));

// ---------- Kernel A (tiny): one thread per (b, window q, channel-half) ----
// Computes the 2x2 argmax code once (vs 196x redundant in R11), writes:
//   mu_out  : pooled max (float4 x4)
//   cmq_g[(b*784+j)*2+hf] = (ql*CH)<<16 | mask16   (ql = q - (j>=392)*98)
//   rm_g [(b*196+q)*2+hf] = packed 4x16-bit row masks (bit cl in slice r
//                           iff channel hf*16+cl has argmax code r)
__global__ void vdp_mask_kernel(const float* __restrict__ mu_in,
                                float* __restrict__ mu_out,
                                uint32_t* __restrict__ cmq_g,
                                unsigned long long* __restrict__ rm_g) {
    const int t = blockIdx.x * 256 + threadIdx.x;
    if (t >= BATCH * NOUT * 2) return;
    const int hf = t & 1;
    const int bq = t >> 1;
    const int q  = bq % NOUT;
    const int b  = bq / NOUT;
    const int qy = q / HO, qx = q - qy * HO;

    const float* base =
        mu_in + (((size_t)b * HIN + 2 * qy) * HIN + 2 * qx) * CH + hf * 16;

    uint32_t kqh = 0;
    #pragma unroll
    for (int g = 0; g < 4; ++g) {
        const float4 v0 = *(const float4*)(base + g * 4);
        const float4 v1 = *(const float4*)(base + CH + g * 4);
        const float4 v2 = *(const float4*)(base + HIN * CH + g * 4);
        const float4 v3 = *(const float4*)(base + HIN * CH + CH + g * 4);
        float mu4[4];
        #pragma unroll
        for (int m = 0; m < 4; ++m) {
            const float e0 = (&v0.x)[m], e1 = (&v1.x)[m],
                        e2 = (&v2.x)[m], e3 = (&v3.x)[m];
            float best = e0; uint32_t k = 0;
            if (e1 > best) { best = e1; k = 1; }   // strict >: TF tie rule
            if (e2 > best) { best = e2; k = 2; }
            if (e3 > best) { best = e3; k = 3; }
            mu4[m] = best;
            kqh |= k << (2 * (g * 4 + m));
        }
        *(float4*)(mu_out + (size_t)bq * CH + hf * 16 + g * 4) =
            make_float4(mu4[0], mu4[1], mu4[2], mu4[3]);
    }

    // cmq entries (4 scattered u32) — local-q offset baked in
    const int ql = q - ((qy >= 7) ? 98 : 0);
    const uint32_t qb = (uint32_t)(ql * CH) << 16;
    const int jb = (2 * qy) * HIN + 2 * qx;
    #pragma unroll
    for (int dj = 0; dj < 4; ++dj) {
        uint32_t mm = 0;
        #pragma unroll
        for (int cl = 0; cl < 16; ++cl)
            mm |= (((kqh >> (2 * cl)) & 3u) == (uint32_t)dj) ? (1u << cl) : 0u;
        const int j = jb + (dj >> 1) * HIN + (dj & 1);
        cmq_g[((size_t)b * NIN + j) * 2 + hf] = qb | mm;
    }

    // packed row-mask u64
    unsigned long long rmpack = 0ull;
    #pragma unroll
    for (int r = 0; r < 4; ++r) {
        uint32_t mm = 0;
        #pragma unroll
        for (int cl = 0; cl < 16; ++cl)
            mm |= (((kqh >> (2 * cl)) & 3u) == (uint32_t)r) ? (1u << cl) : 0u;
        rmpack |= (unsigned long long)mm << (16 * r);
    }
    rm_g[(size_t)bq * 2 + hf] = rmpack;
}

// ---------- Kernel B: block = (b, p, qh), stream + scatter (R11 core) ------
// Phase 0 is now just: 784 coalesced u32 -> LDS, one u64 L2 load per thread.
__global__ __launch_bounds__(256, 6) void vdp_pool_half_kernel(
        const float* __restrict__ sigma_in,
        const uint32_t* __restrict__ cmq_g,
        const unsigned long long* __restrict__ rm_g,
        float* __restrict__ sigma_out)
{
    __shared__ __align__(16) float out_tile[HTILE + 64];   // +64 trash words
    __shared__ uint32_t cmq[JHALF * 2];                    // [jl][half16]

    const int bid = blockIdx.x;
    const int qh  = bid & 1;                 // output-row half
    const int bp  = bid >> 1;                // b*NOUT + p
    const int b   = bp / NOUT;
    const int p   = bp - b * NOUT;
    const int tid = threadIdx.x;
    const int py  = p / HO, px = p - py * HO;

    // ---------------- load masks (coalesced, L2-hot) ------------------------
    {
        const uint32_t* src = cmq_g + ((size_t)b * NIN + qh * JHALF) * 2;
        #pragma unroll
        for (int k = 0; k < 4; ++k) {                  // ceil(784/256) = 4 (!)
            const int w = tid + k * 256;
            if (w < JHALF * 2) cmq[w] = src[w];
        }
    }
    const uint32_t half16 = ((uint32_t)tid >> 2) & 1u;
    const unsigned long long rmpack = rm_g[(size_t)bp * 2 + half16];
    __syncthreads();

    // ---------------- per-thread constants ----------------------------------
    const uint32_t e     = (uint32_t)tid & 7u;         // 16B chunk in 128B row
    const uint32_t shs   = (e & 3u) * 4u;              // nibble shift
    const uint32_t hw    = e * 4u;                     // word offset in row
    const uint32_t posb  = (uint32_t)tid >> 3;         // 0..31
    const uint32_t ibase = (uint32_t)(2 * py) * HIN + 2u * px;
    const uint32_t trash = HTILE + ((uint32_t)tid & 63u);

    // ---------------- Phase 1: dense NT stream + branchless LDS scatter -----
    const float* sb = sigma_in + (size_t)b * NIN * NIN * CH
                    + (size_t)qh * JHALF * CH;         // col-half base
    for (int o = 0; o < OUTER; ++o) {
        f32x4    val[UNROLL];
        uint32_t tab[UNROLL];
        uint32_t rmv[UNROLL];
        #pragma unroll
        for (int u = 0; u < UNROLL; ++u) {
            const uint32_t pos = (uint32_t)(o * UNROLL + u) * 32u + posb;
            const uint32_t r   = pos / JHALF;          // magic-mul
            const uint32_t jl  = pos - r * JHALF;
            const uint32_t i   = ibase + (r >> 1) * HIN + (r & 1u);
            val[u] = __builtin_nontemporal_load(
                (const f32x4*)(sb + ((size_t)i * NIN + jl) * CH + hw));
            tab[u] = cmq[jl * 2 + half16];
            rmv[u] = (uint32_t)(rmpack >> (r * 16u)) & 0xFFFFu;
        }
        #pragma unroll
        for (int u = 0; u < UNROLL; ++u) {
            const uint32_t sel16 = rmv[u] & (tab[u] & 0xFFFFu);
            const uint32_t s4    = (sel16 >> shs) & 0xFu;
            const uint32_t bs    = (tab[u] >> 16) + hw;
            out_tile[(s4 & 1u) ? bs + 0u : trash] = val[u][0];
            out_tile[(s4 & 2u) ? bs + 1u : trash] = val[u][1];
            out_tile[(s4 & 4u) ? bs + 2u : trash] = val[u][2];
            out_tile[(s4 & 8u) ? bs + 3u : trash] = val[u][3];
        }
    }
    __syncthreads();

    // ---------------- Phase 2: contiguous NT half-tile write-out ------------
    {
        const f32x4* srcT = (const f32x4*)out_tile;
        f32x4* dstT = (f32x4*)(sigma_out + (size_t)bp * (NOUT * CH)
                               + (size_t)qh * HTILE);
        for (int w = tid; w < HTILE / 4; w += 256)     // 784 f32x4
            __builtin_nontemporal_store(srcT[w], &dstT[w]);
    }
}

extern "C" void kernel_launch(void* const* d_in, const int* in_sizes, int n_in,
                              void* d_out, int out_size, void* d_ws, size_t ws_size,
                              hipStream_t stream) {
    const float* mu_in    = (const float*)d_in[0];
    const float* sigma_in = (const float*)d_in[1];

    float* mu_out    = (float*)d_out;                      // 8*14*14*32 floats
    float* sigma_out = (float*)d_out + BATCH * NOUT * CH;  // 8*196*196*32 floats

    uint32_t* cmq_g = (uint32_t*)d_ws;                     // 8*784*2 u32 = 50KB
    unsigned long long* rm_g =
        (unsigned long long*)((char*)d_ws + BATCH * NIN * 2 * sizeof(uint32_t));
                                                           // 8*196*2 u64 = 25KB

    {
        const int total = BATCH * NOUT * 2;                // 3136
        vdp_mask_kernel<<<(total + 255) / 256, 256, 0, stream>>>(
            mu_in, mu_out, cmq_g, rm_g);
    }
    vdp_pool_half_kernel<<<BATCH * NOUT * 2, 256, 0, stream>>>(
        sigma_in, cmq_g, rm_g, sigma_out);
}

// Round 14
// 111.525 us; speedup vs baseline: 1.3064x; 1.0524x over previous
//
#include <hip/hip_runtime.h>
#include <stdint.h>

#define BATCH 8
#define HIN   28
#define CH    32
#define HO    14
#define NIN   784                 // 28*28
#define NOUT  196                 // 14*14
#define JHALF 392                 // contiguous j-columns per q-half
#define HTILE (98 * CH)           // 3136 words = 12.5KB output half-tile
#define UNROLL 7
#define OUTER  7                  // 49 items/thread x 256 thr = 12544 items

typedef float f32x4 __attribute__((ext_vector_type(4)));

// ---------- Kernel A (tiny): one thread per (b, window q, channel-half) ----
// Computes the 2x2 argmax code once, writes:
//   mu_out  : pooled max (float4 x4)
//   cmq_g[(b*784+j)*2+hf] = (ql*CH)<<16 | mask16   (ql = q - (j>=392)*98)
//   rm_g [(b*196+q)*2+hf] = packed 4x16-bit row masks (bit cl in slice r
//                           iff channel hf*16+cl has argmax code r)
__global__ void vdp_mask_kernel(const float* __restrict__ mu_in,
                                float* __restrict__ mu_out,
                                uint32_t* __restrict__ cmq_g,
                                unsigned long long* __restrict__ rm_g) {
    const int t = blockIdx.x * 256 + threadIdx.x;
    if (t >= BATCH * NOUT * 2) return;
    const int hf = t & 1;
    const int bq = t >> 1;
    const int q  = bq % NOUT;
    const int b  = bq / NOUT;
    const int qy = q / HO, qx = q - qy * HO;

    const float* base =
        mu_in + (((size_t)b * HIN + 2 * qy) * HIN + 2 * qx) * CH + hf * 16;

    uint32_t kqh = 0;
    #pragma unroll
    for (int g = 0; g < 4; ++g) {
        const float4 v0 = *(const float4*)(base + g * 4);
        const float4 v1 = *(const float4*)(base + CH + g * 4);
        const float4 v2 = *(const float4*)(base + HIN * CH + g * 4);
        const float4 v3 = *(const float4*)(base + HIN * CH + CH + g * 4);
        float mu4[4];
        #pragma unroll
        for (int m = 0; m < 4; ++m) {
            const float e0 = (&v0.x)[m], e1 = (&v1.x)[m],
                        e2 = (&v2.x)[m], e3 = (&v3.x)[m];
            float best = e0; uint32_t k = 0;
            if (e1 > best) { best = e1; k = 1; }   // strict >: TF tie rule
            if (e2 > best) { best = e2; k = 2; }
            if (e3 > best) { best = e3; k = 3; }
            mu4[m] = best;
            kqh |= k << (2 * (g * 4 + m));
        }
        *(float4*)(mu_out + (size_t)bq * CH + hf * 16 + g * 4) =
            make_float4(mu4[0], mu4[1], mu4[2], mu4[3]);
    }

    // cmq entries (4 scattered u32) — local-q offset baked in
    const int ql = q - ((qy >= 7) ? 98 : 0);
    const uint32_t qb = (uint32_t)(ql * CH) << 16;
    const int jb = (2 * qy) * HIN + 2 * qx;
    #pragma unroll
    for (int dj = 0; dj < 4; ++dj) {
        uint32_t mm = 0;
        #pragma unroll
        for (int cl = 0; cl < 16; ++cl)
            mm |= (((kqh >> (2 * cl)) & 3u) == (uint32_t)dj) ? (1u << cl) : 0u;
        const int j = jb + (dj >> 1) * HIN + (dj & 1);
        cmq_g[((size_t)b * NIN + j) * 2 + hf] = qb | mm;
    }

    // packed row-mask u64
    unsigned long long rmpack = 0ull;
    #pragma unroll
    for (int r = 0; r < 4; ++r) {
        uint32_t mm = 0;
        #pragma unroll
        for (int cl = 0; cl < 16; ++cl)
            mm |= (((kqh >> (2 * cl)) & 3u) == (uint32_t)r) ? (1u << cl) : 0u;
        rmpack |= (unsigned long long)mm << (16 * r);
    }
    rm_g[(size_t)bq * 2 + hf] = rmpack;
}

// ---------- Kernel B: block = (b, p, qh) — R13 core + register-resolved ----
// true skip: a pre-pass packs each item's 4-bit select nibble into selp[7]
// (registers). Loads keep counter-pure addresses but are exec-predicated on
// the nibble: dead lanes issue NO memory request; a 128B position row whose
// 8 lanes are all dead (P ~ 12.7%) is never fetched.
__global__ __launch_bounds__(256, 6) void vdp_pool_half_kernel(
        const float* __restrict__ sigma_in,
        const uint32_t* __restrict__ cmq_g,
        const unsigned long long* __restrict__ rm_g,
        float* __restrict__ sigma_out)
{
    __shared__ __align__(16) float out_tile[HTILE + 64];   // +64 trash words
    __shared__ uint32_t cmq[JHALF * 2];                    // [jl][half16]

    const int bid = blockIdx.x;
    const int qh  = bid & 1;                 // output-row half
    const int bp  = bid >> 1;                // b*NOUT + p
    const int b   = bp / NOUT;
    const int p   = bp - b * NOUT;
    const int tid = threadIdx.x;
    const int py  = p / HO, px = p - py * HO;

    // ---------------- load masks (coalesced, L2-hot) ------------------------
    {
        const uint32_t* src = cmq_g + ((size_t)b * NIN + qh * JHALF) * 2;
        #pragma unroll
        for (int k = 0; k < 4; ++k) {                  // ceil(784/256) = 4
            const int w = tid + k * 256;
            if (w < JHALF * 2) cmq[w] = src[w];
        }
    }
    const uint32_t half16 = ((uint32_t)tid >> 2) & 1u;
    const unsigned long long rmpack = rm_g[(size_t)bp * 2 + half16];
    __syncthreads();

    // ---------------- per-thread constants ----------------------------------
    const uint32_t e     = (uint32_t)tid & 7u;         // 16B chunk in 128B row
    const uint32_t shs   = (e & 3u) * 4u;              // nibble shift
    const uint32_t hw    = e * 4u;                     // word offset in row
    const uint32_t posb  = (uint32_t)tid >> 3;         // 0..31
    const uint32_t ibase = (uint32_t)(2 * py) * HIN + 2u * px;
    const uint32_t trash = HTILE + ((uint32_t)tid & 63u);

    // ---------------- pre-pass: pack select nibbles into registers ----------
    uint32_t selp[OUTER];
    #pragma unroll
    for (int o = 0; o < OUTER; ++o) {
        uint32_t sp = 0;
        #pragma unroll
        for (int u = 0; u < UNROLL; ++u) {
            const uint32_t pos = (uint32_t)(o * UNROLL + u) * 32u + posb;
            const uint32_t r   = pos / JHALF;          // magic-mul
            const uint32_t jl  = pos - r * JHALF;
            const uint32_t sel16 =
                ((uint32_t)(rmpack >> (r * 16u)) & cmq[jl * 2 + half16]) & 0xFFFFu;
            sp |= ((sel16 >> shs) & 0xFu) << (4 * u);
        }
        selp[o] = sp;
    }

    // ---------------- Phase 1: predicated dense stream + LDS scatter --------
    const float* sb = sigma_in + (size_t)b * NIN * NIN * CH
                    + (size_t)qh * JHALF * CH;         // col-half base
    for (int o = 0; o < OUTER; ++o) {
        f32x4    val[UNROLL];
        uint32_t tab[UNROLL];
        const uint32_t sp = selp[o];
        #pragma unroll
        for (int u = 0; u < UNROLL; ++u) {
            const uint32_t pos = (uint32_t)(o * UNROLL + u) * 32u + posb;
            const uint32_t r   = pos / JHALF;
            const uint32_t jl  = pos - r * JHALF;
            const uint32_t i   = ibase + (r >> 1) * HIN + (r & 1u);
            val[u] = (f32x4){0.0f, 0.0f, 0.0f, 0.0f};
            if ((sp >> (4 * u)) & 0xFu)                // dead lanes: NO request
                val[u] = __builtin_nontemporal_load(
                    (const f32x4*)(sb + ((size_t)i * NIN + jl) * CH + hw));
            tab[u] = cmq[jl * 2 + half16];
        }
        #pragma unroll
        for (int u = 0; u < UNROLL; ++u) {
            const uint32_t s4 = (sp >> (4 * u)) & 0xFu;
            const uint32_t bs = (tab[u] >> 16) + hw;
            out_tile[(s4 & 1u) ? bs + 0u : trash] = val[u][0];
            out_tile[(s4 & 2u) ? bs + 1u : trash] = val[u][1];
            out_tile[(s4 & 4u) ? bs + 2u : trash] = val[u][2];
            out_tile[(s4 & 8u) ? bs + 3u : trash] = val[u][3];
        }
    }
    __syncthreads();

    // ---------------- Phase 2: contiguous NT half-tile write-out ------------
    {
        const f32x4* srcT = (const f32x4*)out_tile;
        f32x4* dstT = (f32x4*)(sigma_out + (size_t)bp * (NOUT * CH)
                               + (size_t)qh * HTILE);
        for (int w = tid; w < HTILE / 4; w += 256)     // 784 f32x4
            __builtin_nontemporal_store(srcT[w], &dstT[w]);
    }
}

extern "C" void kernel_launch(void* const* d_in, const int* in_sizes, int n_in,
                              void* d_out, int out_size, void* d_ws, size_t ws_size,
                              hipStream_t stream) {
    const float* mu_in    = (const float*)d_in[0];
    const float* sigma_in = (const float*)d_in[1];

    float* mu_out    = (float*)d_out;                      // 8*14*14*32 floats
    float* sigma_out = (float*)d_out + BATCH * NOUT * CH;  // 8*196*196*32 floats

    uint32_t* cmq_g = (uint32_t*)d_ws;                     // 8*784*2 u32 = 50KB
    unsigned long long* rm_g =
        (unsigned long long*)((char*)d_ws + BATCH * NIN * 2 * sizeof(uint32_t));
                                                           // 8*196*2 u64 = 25KB

    {
        const int total = BATCH * NOUT * 2;                // 3136
        vdp_mask_kernel<<<(total + 255) / 256, 256, 0, stream>>>(
            mu_in, mu_out, cmq_g, rm_g);
    }
    vdp_pool_half_kernel<<<BATCH * NOUT * 2, 256, 0, stream>>>(
        sigma_in, cmq_g, rm_g, sigma_out);
}